// Round 2
// baseline (362.682 us; speedup 1.0000x reference)
//
#include <hip/hip_runtime.h>
#include <stdint.h>

// Problem constants (PureSAGEConv): N=50000, C_in=512, C_out=512, E=800000
#define CI 512
#define CO 512

typedef __attribute__((ext_vector_type(4))) float f32x4;
typedef __attribute__((ext_vector_type(8))) __bf16 bf16x8;

__device__ __forceinline__ unsigned short f2bf_bits(float f) {
  union { float f; unsigned int u; } v; v.f = f;
  unsigned int u = v.u;
  unsigned int lsb = (u >> 16) & 1u;
  u += 0x7fffu + lsb;                 // round-to-nearest-even
  return (unsigned short)(u >> 16);
}

// ---- f32 -> bf16 conversion (vectorized float4 -> ushort4) ----
__global__ void k_convert(const float* __restrict__ in,
                          unsigned short* __restrict__ out, int n4) {
  int i = blockIdx.x * 256 + threadIdx.x;
  if (i < n4) {
    float4 v = reinterpret_cast<const float4*>(in)[i];
    ushort4 o;
    o.x = f2bf_bits(v.x); o.y = f2bf_bits(v.y);
    o.z = f2bf_bits(v.z); o.w = f2bf_bits(v.w);
    reinterpret_cast<ushort4*>(out)[i] = o;
  }
}

// ---- degree histogram ----
__global__ void k_degree(const int* __restrict__ dst, int* __restrict__ cnt, int E) {
  int e = blockIdx.x * 256 + threadIdx.x;
  if (e < E) atomicAdd(&cnt[dst[e]], 1);
}

// ---- hierarchical scan: cnt[n] -> rowptr[n+1] (exclusive, rowptr[0]=0) ----
__global__ void k_bsum(const int* __restrict__ cnt, int* __restrict__ bsum, int n) {
  int t = threadIdx.x;
  int i = blockIdx.x * 256 + t;
  int v = (i < n) ? cnt[i] : 0;
  #pragma unroll
  for (int off = 32; off; off >>= 1) v += __shfl_down(v, off, 64);
  __shared__ int ws[4];
  if ((t & 63) == 0) ws[t >> 6] = v;
  __syncthreads();
  if (t == 0) bsum[blockIdx.x] = ws[0] + ws[1] + ws[2] + ws[3];
}

__global__ void k_scanb(const int* __restrict__ bsum, int* __restrict__ boff, int nb) {
  // nb <= 256
  int t = threadIdx.x, lane = t & 63, w = t >> 6;
  int v = (t < nb) ? bsum[t] : 0;
  int s = v;
  #pragma unroll
  for (int off = 1; off < 64; off <<= 1) {
    int u = __shfl_up(s, off, 64);
    if (lane >= off) s += u;
  }
  __shared__ int ws[4];
  if (lane == 63) ws[w] = s;
  __syncthreads();
  int add = 0;
  for (int j = 0; j < w; ++j) add += ws[j];
  if (t < nb) boff[t] = s + add - v;   // exclusive block offset
}

__global__ void k_scanf(const int* __restrict__ cnt, const int* __restrict__ boff,
                        int* __restrict__ rowptr, int n) {
  int t = threadIdx.x, lane = t & 63, w = t >> 6;
  int i = blockIdx.x * 256 + t;
  int v = (i < n) ? cnt[i] : 0;
  int s = v;
  #pragma unroll
  for (int off = 1; off < 64; off <<= 1) {
    int u = __shfl_up(s, off, 64);
    if (lane >= off) s += u;
  }
  __shared__ int ws[4];
  if (lane == 63) ws[w] = s;
  __syncthreads();
  int add = boff[blockIdx.x];
  for (int j = 0; j < w; ++j) add += ws[j];
  if (i < n) rowptr[i + 1] = s + add;
  if (i == 0) rowptr[0] = 0;
}

// ---- counting-sort fill of CSR neighbor lists ----
__global__ void k_fill(const int* __restrict__ src, const int* __restrict__ dst,
                       const int* __restrict__ rowptr, int* __restrict__ cursor,
                       int* __restrict__ csr, int E) {
  int e = blockIdx.x * 256 + threadIdx.x;
  if (e < E) {
    int d = dst[e];
    int pos = atomicAdd(&cursor[d], 1);
    csr[rowptr[d] + pos] = src[e];
  }
}

// ---- bf16 accumulate helper ----
__device__ __forceinline__ void acc8(float* s, uint4 r) {
  const unsigned int u[4] = {r.x, r.y, r.z, r.w};
  #pragma unroll
  for (int k = 0; k < 4; ++k) {
    union { unsigned int u; float f; } lo, hi;
    lo.u = u[k] << 16;
    hi.u = u[k] & 0xffff0000u;
    s[2 * k]     += lo.f;
    s[2 * k + 1] += hi.f;
  }
}

#define BM 128
#define BN 128
#define BK 32

// ---- shared GEMM half-tile body ----
// Computes a BMxBN tile of A[M][512] . W_half[512][512]^T.
// SECOND=false: A=xb,   W columns [0,512),   out = acc + bias
// SECOND=true : A=meanb,W columns [512,1024),out += acc
template <bool SECOND>
__device__ __forceinline__ void gemm_half(
    const unsigned short* __restrict__ A,
    const unsigned short* __restrict__ Wb,
    const float* __restrict__ bias,
    float* __restrict__ out, int M, int tm, int tn,
    unsigned short* lds_a, unsigned short* lds_b) {
  const int tid = threadIdx.x;
  const int m0 = tm * BM, n0 = tn * BN;
  const int lane = tid & 63, w = tid >> 6;
  const int wm = w >> 1, wn = w & 1;
  const int lrow = lane & 15, lk = (lane >> 4) * 8;
  const int r0 = tid >> 2, c8 = (tid & 3) << 3;  // staging: 4 threads/row
  const int koff = SECOND ? CI : 0;

  f32x4 acc[4][4] = {};

  for (int k0 = 0; k0 < CI; k0 += BK) {
    __syncthreads();
    {
      int gr0 = m0 + r0;      if (gr0 >= M) gr0 = M - 1;
      int gr1 = m0 + r0 + 64; if (gr1 >= M) gr1 = M - 1;
      __builtin_amdgcn_global_load_lds(
        (const __attribute__((address_space(1))) unsigned int*)(uintptr_t)(A + (size_t)gr0 * CI + k0 + c8),
        (__attribute__((address_space(3))) unsigned int*)(uintptr_t)(&lds_a[(size_t)tid * 8]), 16, 0, 0);
      __builtin_amdgcn_global_load_lds(
        (const __attribute__((address_space(1))) unsigned int*)(uintptr_t)(A + (size_t)gr1 * CI + k0 + c8),
        (__attribute__((address_space(3))) unsigned int*)(uintptr_t)(&lds_a[(size_t)(256 + tid) * 8]), 16, 0, 0);
      __builtin_amdgcn_global_load_lds(
        (const __attribute__((address_space(1))) unsigned int*)(uintptr_t)(Wb + (size_t)(n0 + r0) * (2 * CI) + koff + k0 + c8),
        (__attribute__((address_space(3))) unsigned int*)(uintptr_t)(&lds_b[(size_t)tid * 8]), 16, 0, 0);
      __builtin_amdgcn_global_load_lds(
        (const __attribute__((address_space(1))) unsigned int*)(uintptr_t)(Wb + (size_t)(n0 + r0 + 64) * (2 * CI) + koff + k0 + c8),
        (__attribute__((address_space(3))) unsigned int*)(uintptr_t)(&lds_b[(size_t)(256 + tid) * 8]), 16, 0, 0);
    }
    __syncthreads();
    bf16x8 af[4], bfr[4];
    #pragma unroll
    for (int mi = 0; mi < 4; ++mi)
      af[mi] = *reinterpret_cast<const bf16x8*>(&lds_a[(wm * 64 + mi * 16 + lrow) * BK + lk]);
    #pragma unroll
    for (int ni = 0; ni < 4; ++ni)
      bfr[ni] = *reinterpret_cast<const bf16x8*>(&lds_b[(wn * 64 + ni * 16 + lrow) * BK + lk]);
    #pragma unroll
    for (int mi = 0; mi < 4; ++mi)
      #pragma unroll
      for (int ni = 0; ni < 4; ++ni)
        acc[mi][ni] = __builtin_amdgcn_mfma_f32_16x16x32_bf16(af[mi], bfr[ni], acc[mi][ni], 0, 0, 0);
  }

  #pragma unroll
  for (int mi = 0; mi < 4; ++mi) {
    #pragma unroll
    for (int ni = 0; ni < 4; ++ni) {
      const int col = n0 + wn * 64 + ni * 16 + lrow;
      const float bb = SECOND ? 0.f : bias[col];
      #pragma unroll
      for (int j = 0; j < 4; ++j) {
        int row = m0 + wm * 64 + mi * 16 + (lane >> 4) * 4 + j;
        if (row < M) {
          size_t idx = (size_t)row * CO + col;
          if (SECOND) out[idx] += acc[mi][ni][j];
          else        out[idx] = acc[mi][ni][j] + bb;
        }
      }
    }
  }
}

// ---- mega-kernel: neighbor-mean aggregate blocks interleaved with
//      GEMM1 (out = x.W1^T + b) blocks. Aggregate is memory-bound
//      (MfmaUtil 0, HBM 45%); GEMM1's MFMA work hides under it. ----
__global__ __launch_bounds__(256) void k_agg_gemm1(
    const unsigned short* __restrict__ xb,
    const int* __restrict__ rowptr,
    const int* __restrict__ csr,
    unsigned short* __restrict__ meanb, int Nn,
    const unsigned short* __restrict__ Wb,
    const float* __restrict__ bias,
    float* __restrict__ out, int M,
    int stride, int nG) {
  __shared__ unsigned short lds_a[BM * BK];
  __shared__ unsigned short lds_b[BN * BK];
  const int bid = blockIdx.x;
  const int g = bid / stride;
  const int rr = bid - g * stride;

  if (rr == 0) {
    // GEMM1 tile. Dispatcher places bid on XCD bid%8 = (stride*g)%8; with
    // stride%8==1 that is g%8. Chunked remap gives each XCD a contiguous
    // range of tile ids so the 4 n-tiles of an m-stripe share one L2.
    int t = g;
    if ((stride & 7) == 1) {
      const int q = nG >> 3, r = nG & 7;
      const int xcd = g & 7, j = g >> 3;
      t = (xcd < r ? xcd * (q + 1) : r * (q + 1) + (xcd - r) * q) + j;
    }
    gemm_half<false>(xb, Wb, bias, out, M, t >> 2, t & 3, lds_a, lds_b);
    return;
  }

  // ---- aggregate path: ONE WAVE per node, 16B/lane gathers ----
  const int aid = bid - g - 1;                  // aggregate block index
  const int wid = aid * 4 + (threadIdx.x >> 6); // node id
  const int lane = threadIdx.x & 63;
  if (wid >= Nn) return;
  const int beg = rowptr[wid];
  const int deg = rowptr[wid + 1] - beg;
  float s[8] = {};
  const size_t laneoff = (size_t)lane * 8;

  for (int base = 0; base < deg; base += 64) {
    const int rem = deg - base;
    const int cnt = rem < 64 ? rem : 64;
    int nidx = 0;
    if (lane < cnt) nidx = csr[beg + base + lane];   // 64 indices per load
    int j = 0;
    for (; j + 4 <= cnt; j += 4) {                   // 4 gathers in flight
      int u0 = __shfl(nidx, j, 64);
      int u1 = __shfl(nidx, j + 1, 64);
      int u2 = __shfl(nidx, j + 2, 64);
      int u3 = __shfl(nidx, j + 3, 64);
      uint4 r0 = *reinterpret_cast<const uint4*>(xb + (size_t)u0 * CI + laneoff);
      uint4 r1 = *reinterpret_cast<const uint4*>(xb + (size_t)u1 * CI + laneoff);
      uint4 r2 = *reinterpret_cast<const uint4*>(xb + (size_t)u2 * CI + laneoff);
      uint4 r3 = *reinterpret_cast<const uint4*>(xb + (size_t)u3 * CI + laneoff);
      acc8(s, r0); acc8(s, r1); acc8(s, r2); acc8(s, r3);
    }
    for (; j < cnt; ++j) {
      int u = __shfl(nidx, j, 64);
      uint4 r = *reinterpret_cast<const uint4*>(xb + (size_t)u * CI + laneoff);
      acc8(s, r);
    }
  }

  const float inv = 1.f / fmaxf((float)deg, 1.f);
  unsigned short ob[8];
  #pragma unroll
  for (int k = 0; k < 8; ++k) ob[k] = f2bf_bits(s[k] * inv);
  uint4 wv;
  wv.x = (unsigned int)ob[0] | ((unsigned int)ob[1] << 16);
  wv.y = (unsigned int)ob[2] | ((unsigned int)ob[3] << 16);
  wv.z = (unsigned int)ob[4] | ((unsigned int)ob[5] << 16);
  wv.w = (unsigned int)ob[6] | ((unsigned int)ob[7] << 16);
  *reinterpret_cast<uint4*>(meanb + (size_t)wid * CI + laneoff) = wv;
}

// ---- GEMM2: out += mean . W2^T ----
__global__ __launch_bounds__(256) void k_gemm2(
    const unsigned short* __restrict__ meanb,
    const unsigned short* __restrict__ Wb,
    float* __restrict__ out, int M) {
  __shared__ unsigned short lds_a[BM * BK];
  __shared__ unsigned short lds_b[BN * BK];

  // Bijective XCD-aware swizzle (m204; nwg not divisible by 8).
  const int nwg = gridDim.x;
  const int q = nwg >> 3, r = nwg & 7;
  const int xcd = blockIdx.x & 7, lid = blockIdx.x >> 3;
  const int wg = (xcd < r ? xcd * (q + 1) : r * (q + 1) + (xcd - r) * q) + lid;

  gemm_half<true>(meanb, Wb, nullptr, out, M, wg >> 2, wg & 3, lds_a, lds_b);
}

extern "C" void kernel_launch(void* const* d_in, const int* in_sizes, int n_in,
                              void* d_out, int out_size, void* d_ws, size_t ws_size,
                              hipStream_t stream) {
  (void)n_in; (void)out_size; (void)ws_size;
  const float* x    = (const float*)d_in[0];
  const int*   ei   = (const int*)d_in[1];
  const float* W    = (const float*)d_in[2];
  const float* bias = (const float*)d_in[3];
  float* out = (float*)d_out;

  const int Nn = in_sizes[0] / CI;     // 50000
  const int E  = in_sizes[1] / 2;      // 800000
  const int* src = ei;
  const int* dst = ei + E;

  const int nblk = (Nn + 255) / 256;   // 196 scan blocks

  // workspace layout (~107 MB):
  int* cnt    = (int*)d_ws;            // [Nn]
  int* cursor = cnt + Nn;              // [Nn]
  int* rowptr = cursor + Nn;           // [Nn+1]
  int* bsum   = rowptr + (Nn + 1);     // [nblk]
  int* boff   = bsum + nblk;           // [nblk]
  int* csr    = boff + nblk;           // [E]
  uintptr_t p = (uintptr_t)(csr + E);
  p = (p + 255) & ~(uintptr_t)255;
  unsigned short* xb    = (unsigned short*)p;           // [Nn*CI] bf16
  unsigned short* meanb = xb + (size_t)Nn * CI;         // [Nn*CI] bf16
  unsigned short* Wb    = meanb + (size_t)Nn * CI;      // [CO*2CI] bf16

  hipMemsetAsync(cnt, 0, (size_t)2 * Nn * sizeof(int), stream);  // cnt + cursor

  const int nx4 = (Nn * CI) / 4;          // 6,400,000
  const int nw4 = (CO * 2 * CI) / 4;      // 131,072
  k_convert<<<(nx4 + 255) / 256, 256, 0, stream>>>(x, xb, nx4);
  k_convert<<<(nw4 + 255) / 256, 256, 0, stream>>>(W, Wb, nw4);
  k_degree<<<(E + 255) / 256, 256, 0, stream>>>(dst, cnt, E);
  k_bsum<<<nblk, 256, 0, stream>>>(cnt, bsum, Nn);
  k_scanb<<<1, 256, 0, stream>>>(bsum, boff, nblk);
  k_scanf<<<nblk, 256, 0, stream>>>(cnt, boff, rowptr, Nn);
  k_fill<<<(E + 255) / 256, 256, 0, stream>>>(src, dst, rowptr, cursor, csr, E);

  const int mtiles = (Nn + BM - 1) / BM;   // 391
  const int nG = mtiles * (CO / BN);       // 1564 GEMM tiles
  const int nAgg = (Nn + 3) / 4;           // 12500 aggregate blocks
  int s = nAgg / nG + 2;                   // interleave stride (=9 here)
  if (!(s & 1)) s += 1;                    // odd => gemm blocks rotate XCDs
  // mega-kernel: aggregate + GEMM1 (x.W1^T + b) overlapped
  k_agg_gemm1<<<s * nG, 256, 0, stream>>>(xb, rowptr, csr, meanb, Nn,
                                          Wb, bias, out, Nn, s, nG);
  // GEMM2: out += mean.W2^T
  k_gemm2<<<nG, 256, 0, stream>>>(meanb, Wb, out, Nn);
}

// Round 3
// 328.731 us; speedup vs baseline: 1.1033x; 1.1033x over previous
//
#include <hip/hip_runtime.h>
#include <stdint.h>

// Problem constants (PureSAGEConv): N=50000, C_in=512, C_out=512, E=800000
#define CI 512
#define CO 512

typedef __attribute__((ext_vector_type(4))) float f32x4;
typedef __attribute__((ext_vector_type(8))) __bf16 bf16x8;

__device__ __forceinline__ unsigned short f2bf_bits(float f) {
  union { float f; unsigned int u; } v; v.f = f;
  unsigned int u = v.u;
  unsigned int lsb = (u >> 16) & 1u;
  u += 0x7fffu + lsb;                 // round-to-nearest-even
  return (unsigned short)(u >> 16);
}

// ---- merged: convert x, convert W, degree histogram (block-range split) ----
__global__ void k_prep(const float* __restrict__ x, unsigned short* __restrict__ xb, int nx4,
                       const float* __restrict__ W, unsigned short* __restrict__ Wb, int nw4,
                       const int* __restrict__ dst, int* __restrict__ cnt, int E,
                       int bx, int bw) {
  const int b = blockIdx.x;
  if (b < bx) {
    int i = b * 256 + threadIdx.x;
    if (i < nx4) {
      float4 v = reinterpret_cast<const float4*>(x)[i];
      ushort4 o;
      o.x = f2bf_bits(v.x); o.y = f2bf_bits(v.y);
      o.z = f2bf_bits(v.z); o.w = f2bf_bits(v.w);
      reinterpret_cast<ushort4*>(xb)[i] = o;
    }
  } else if (b < bx + bw) {
    int i = (b - bx) * 256 + threadIdx.x;
    if (i < nw4) {
      float4 v = reinterpret_cast<const float4*>(W)[i];
      ushort4 o;
      o.x = f2bf_bits(v.x); o.y = f2bf_bits(v.y);
      o.z = f2bf_bits(v.z); o.w = f2bf_bits(v.w);
      reinterpret_cast<ushort4*>(Wb)[i] = o;
    }
  } else {
    int e = (b - bx - bw) * 256 + threadIdx.x;
    if (e < E) atomicAdd(&cnt[dst[e]], 1);
  }
}

// ---- hierarchical scan: cnt[n] -> rowptr[n+1] (exclusive, rowptr[0]=0) ----
__global__ void k_bsum(const int* __restrict__ cnt, int* __restrict__ bsum, int n) {
  int t = threadIdx.x;
  int i = blockIdx.x * 256 + t;
  int v = (i < n) ? cnt[i] : 0;
  #pragma unroll
  for (int off = 32; off; off >>= 1) v += __shfl_down(v, off, 64);
  __shared__ int ws[4];
  if ((t & 63) == 0) ws[t >> 6] = v;
  __syncthreads();
  if (t == 0) bsum[blockIdx.x] = ws[0] + ws[1] + ws[2] + ws[3];
}

__global__ void k_scanb(const int* __restrict__ bsum, int* __restrict__ boff, int nb) {
  // nb <= 256
  int t = threadIdx.x, lane = t & 63, w = t >> 6;
  int v = (t < nb) ? bsum[t] : 0;
  int s = v;
  #pragma unroll
  for (int off = 1; off < 64; off <<= 1) {
    int u = __shfl_up(s, off, 64);
    if (lane >= off) s += u;
  }
  __shared__ int ws[4];
  if (lane == 63) ws[w] = s;
  __syncthreads();
  int add = 0;
  for (int j = 0; j < w; ++j) add += ws[j];
  if (t < nb) boff[t] = s + add - v;   // exclusive block offset
}

__global__ void k_scanf(const int* __restrict__ cnt, const int* __restrict__ boff,
                        int* __restrict__ rowptr, int n) {
  int t = threadIdx.x, lane = t & 63, w = t >> 6;
  int i = blockIdx.x * 256 + t;
  int v = (i < n) ? cnt[i] : 0;
  int s = v;
  #pragma unroll
  for (int off = 1; off < 64; off <<= 1) {
    int u = __shfl_up(s, off, 64);
    if (lane >= off) s += u;
  }
  __shared__ int ws[4];
  if (lane == 63) ws[w] = s;
  __syncthreads();
  int add = boff[blockIdx.x];
  for (int j = 0; j < w; ++j) add += ws[j];
  if (i < n) rowptr[i + 1] = s + add;
  if (i == 0) rowptr[0] = 0;
}

// ---- counting-sort fill of CSR neighbor lists ----
__global__ void k_fill(const int* __restrict__ src, const int* __restrict__ dst,
                       const int* __restrict__ rowptr, int* __restrict__ cursor,
                       int* __restrict__ csr, int E) {
  int e = blockIdx.x * 256 + threadIdx.x;
  if (e < E) {
    int d = dst[e];
    int pos = atomicAdd(&cursor[d], 1);
    csr[rowptr[d] + pos] = src[e];
  }
}

// ---- per-node neighbor mean: ONE WAVE per node, 16B/lane gathers ----
__device__ __forceinline__ void acc8(float* s, uint4 r) {
  const unsigned int u[4] = {r.x, r.y, r.z, r.w};
  #pragma unroll
  for (int k = 0; k < 4; ++k) {
    union { unsigned int u; float f; } lo, hi;
    lo.u = u[k] << 16;
    hi.u = u[k] & 0xffff0000u;
    s[2 * k]     += lo.f;
    s[2 * k + 1] += hi.f;
  }
}

__global__ __launch_bounds__(256) void k_aggregate(
    const unsigned short* __restrict__ xb,
    const int* __restrict__ rowptr,
    const int* __restrict__ csr,
    unsigned short* __restrict__ meanb, int Nn) {
  const int wid = blockIdx.x * 4 + (threadIdx.x >> 6);   // node id
  const int lane = threadIdx.x & 63;
  if (wid >= Nn) return;
  const int beg = rowptr[wid];
  const int deg = rowptr[wid + 1] - beg;
  float s[8] = {};
  const size_t laneoff = (size_t)lane * 8;

  for (int base = 0; base < deg; base += 64) {
    const int rem = deg - base;
    const int cnt = rem < 64 ? rem : 64;
    int nidx = 0;
    if (lane < cnt) nidx = csr[beg + base + lane];   // 64 indices per load
    int j = 0;
    for (; j + 4 <= cnt; j += 4) {                   // 4 gathers in flight
      int u0 = __shfl(nidx, j, 64);
      int u1 = __shfl(nidx, j + 1, 64);
      int u2 = __shfl(nidx, j + 2, 64);
      int u3 = __shfl(nidx, j + 3, 64);
      uint4 r0 = *reinterpret_cast<const uint4*>(xb + (size_t)u0 * CI + laneoff);
      uint4 r1 = *reinterpret_cast<const uint4*>(xb + (size_t)u1 * CI + laneoff);
      uint4 r2 = *reinterpret_cast<const uint4*>(xb + (size_t)u2 * CI + laneoff);
      uint4 r3 = *reinterpret_cast<const uint4*>(xb + (size_t)u3 * CI + laneoff);
      acc8(s, r0); acc8(s, r1); acc8(s, r2); acc8(s, r3);
    }
    for (; j < cnt; ++j) {
      int u = __shfl(nidx, j, 64);
      uint4 r = *reinterpret_cast<const uint4*>(xb + (size_t)u * CI + laneoff);
      acc8(s, r);
    }
  }

  const float inv = 1.f / fmaxf((float)deg, 1.f);
  unsigned short ob[8];
  #pragma unroll
  for (int k = 0; k < 8; ++k) ob[k] = f2bf_bits(s[k] * inv);
  uint4 w;
  w.x = (unsigned int)ob[0] | ((unsigned int)ob[1] << 16);
  w.y = (unsigned int)ob[2] | ((unsigned int)ob[3] << 16);
  w.z = (unsigned int)ob[4] | ((unsigned int)ob[5] << 16);
  w.w = (unsigned int)ob[6] | ((unsigned int)ob[7] << 16);
  *reinterpret_cast<uint4*>(meanb + (size_t)wid * CI + laneoff) = w;
}

// ---- bf16 MFMA GEMM: out[M][512] = [xb|meanb][M][1024] . Wb[512][1024]^T + b ----
// BK=64, single-buffered LDS (2x16KB), T2 chunk-swizzle (pre-swizzled global
// source + swizzled ds_read; global_load_lds dest stays linear - rule #21).
#define BM 128
#define BN 128
#define BK 64

__global__ __launch_bounds__(256) void k_gemm(
    const unsigned short* __restrict__ xb,
    const unsigned short* __restrict__ meanb,
    const unsigned short* __restrict__ Wb,
    const float* __restrict__ bias,
    float* __restrict__ out, int M) {
  __shared__ unsigned short lds_a[BM * BK];   // 16 KB
  __shared__ unsigned short lds_b[BN * BK];   // 16 KB
  const int tid = threadIdx.x;
  const int ntn = CO / BN;                       // 4

  // Bijective XCD-aware swizzle (m204 formula; nwg=1564 is NOT %8==0).
  const int nwg = gridDim.x;
  const int NX = 8;
  const int q = nwg / NX, r = nwg % NX;
  const int xcd = blockIdx.x % NX, lid = blockIdx.x / NX;
  const int wg = (xcd < r ? xcd * (q + 1) : r * (q + 1) + (xcd - r) * q) + lid;

  const int tm = wg / ntn, tn = wg % ntn;
  const int m0 = tm * BM, n0 = tn * BN;
  const int lane = tid & 63, w = tid >> 6;
  const int wm = w >> 1, wn = w & 1;
  const int lrow = lane & 15;

  // Staging geometry: 4 x (256 threads x 16B) = 128 rows x 64 cols (bf16).
  // chunk idx = i*256+tid; row = idx>>3; stored-chunk sc = idx&7;
  // source chunk = sc ^ (row&7)  (XOR swizzle, involution).
  int arow[4], gra[4], acol8[4];               // hoisted out of K-loop
  #pragma unroll
  for (int i = 0; i < 4; ++i) {
    int idx = i * 256 + tid;
    arow[i] = idx >> 3;
    int sc = idx & 7;
    acol8[i] = (sc ^ (arow[i] & 7)) * 8;       // element offset within row
    int g = m0 + arow[i];
    gra[i] = g < M ? g : M - 1;
  }

  f32x4 acc[4][4] = {};

  #pragma unroll
  for (int half = 0; half < 2; ++half) {
    const unsigned short* __restrict__ A = half ? meanb : xb;
    const int koff = half * CI;
    for (int k0 = 0; k0 < CI; k0 += BK) {
      __syncthreads();
      #pragma unroll
      for (int i = 0; i < 4; ++i) {
        __builtin_amdgcn_global_load_lds(
          (const __attribute__((address_space(1))) unsigned int*)(uintptr_t)(A + (size_t)gra[i] * CI + k0 + acol8[i]),
          (__attribute__((address_space(3))) unsigned int*)(uintptr_t)(&lds_a[(size_t)(i * 256 + tid) * 8]), 16, 0, 0);
        __builtin_amdgcn_global_load_lds(
          (const __attribute__((address_space(1))) unsigned int*)(uintptr_t)(Wb + (size_t)(n0 + arow[i]) * (2 * CI) + koff + k0 + acol8[i]),
          (__attribute__((address_space(3))) unsigned int*)(uintptr_t)(&lds_b[(size_t)(i * 256 + tid) * 8]), 16, 0, 0);
      }
      __syncthreads();
      #pragma unroll
      for (int kk = 0; kk < 2; ++kk) {
        const int crd = (lane >> 4) + 4 * kk;  // which 8-elem chunk of the row
        bf16x8 af[4], bfr[4];
        #pragma unroll
        for (int mi = 0; mi < 4; ++mi) {
          const int rr = wm * 64 + mi * 16 + lrow;
          af[mi] = *reinterpret_cast<const bf16x8*>(&lds_a[rr * BK + ((crd ^ (rr & 7)) * 8)]);
        }
        #pragma unroll
        for (int ni = 0; ni < 4; ++ni) {
          const int rr = wn * 64 + ni * 16 + lrow;
          bfr[ni] = *reinterpret_cast<const bf16x8*>(&lds_b[rr * BK + ((crd ^ (rr & 7)) * 8)]);
        }
        #pragma unroll
        for (int mi = 0; mi < 4; ++mi)
          #pragma unroll
          for (int ni = 0; ni < 4; ++ni)
            acc[mi][ni] = __builtin_amdgcn_mfma_f32_16x16x32_bf16(af[mi], bfr[ni], acc[mi][ni], 0, 0, 0);
      }
    }
  }

  #pragma unroll
  for (int mi = 0; mi < 4; ++mi) {
    #pragma unroll
    for (int ni = 0; ni < 4; ++ni) {
      const int col = n0 + wn * 64 + ni * 16 + lrow;
      const float bb = bias[col];
      #pragma unroll
      for (int j = 0; j < 4; ++j) {
        int row = m0 + wm * 64 + mi * 16 + (lane >> 4) * 4 + j;
        if (row < M) out[(size_t)row * CO + col] = acc[mi][ni][j] + bb;
      }
    }
  }
}

extern "C" void kernel_launch(void* const* d_in, const int* in_sizes, int n_in,
                              void* d_out, int out_size, void* d_ws, size_t ws_size,
                              hipStream_t stream) {
  (void)n_in; (void)out_size; (void)ws_size;
  const float* x    = (const float*)d_in[0];
  const int*   ei   = (const int*)d_in[1];
  const float* W    = (const float*)d_in[2];
  const float* bias = (const float*)d_in[3];
  float* out = (float*)d_out;

  const int Nn = in_sizes[0] / CI;     // 50000
  const int E  = in_sizes[1] / 2;      // 800000
  const int* src = ei;
  const int* dst = ei + E;

  const int nblk = (Nn + 255) / 256;   // 196 scan blocks

  // workspace layout (~107 MB):
  int* cnt    = (int*)d_ws;            // [Nn]
  int* cursor = cnt + Nn;              // [Nn]
  int* rowptr = cursor + Nn;           // [Nn+1]
  int* bsum   = rowptr + (Nn + 1);     // [nblk]
  int* boff   = bsum + nblk;           // [nblk]
  int* csr    = boff + nblk;           // [E]
  uintptr_t p = (uintptr_t)(csr + E);
  p = (p + 255) & ~(uintptr_t)255;
  unsigned short* xb    = (unsigned short*)p;           // [Nn*CI] bf16
  unsigned short* meanb = xb + (size_t)Nn * CI;         // [Nn*CI] bf16
  unsigned short* Wb    = meanb + (size_t)Nn * CI;      // [CO*2CI] bf16

  hipMemsetAsync(cnt, 0, (size_t)2 * Nn * sizeof(int), stream);  // cnt + cursor

  const int nx4 = (Nn * CI) / 4;          // 6,400,000
  const int nw4 = (CO * 2 * CI) / 4;      // 131,072
  const int bx = (nx4 + 255) / 256;       // 25000
  const int bw = (nw4 + 255) / 256;       // 512
  const int be = (E + 255) / 256;         // 3125
  k_prep<<<bx + bw + be, 256, 0, stream>>>(x, xb, nx4, W, Wb, nw4, dst, cnt, E, bx, bw);
  k_bsum<<<nblk, 256, 0, stream>>>(cnt, bsum, Nn);
  k_scanb<<<1, 256, 0, stream>>>(bsum, boff, nblk);
  k_scanf<<<nblk, 256, 0, stream>>>(cnt, boff, rowptr, Nn);
  k_fill<<<(E + 255) / 256, 256, 0, stream>>>(src, dst, rowptr, cursor, csr, E);
  k_aggregate<<<(Nn + 3) / 4, 256, 0, stream>>>(xb, rowptr, csr, meanb, Nn);

  const int mtiles = (Nn + BM - 1) / BM;  // 391
  k_gemm<<<mtiles * (CO / BN), 256, 0, stream>>>(xb, meanb, Wb, bias, out, Nn);
}

// Round 4
// 314.682 us; speedup vs baseline: 1.1525x; 1.0446x over previous
//
#include <hip/hip_runtime.h>
#include <stdint.h>

// Problem constants (PureSAGEConv): N=50000, C_in=512, C_out=512, E=800000
#define CI 512
#define CO 512
#define CPAD 8   // counter padding stride (ints): 4 counters per 128B line

typedef __attribute__((ext_vector_type(4))) float f32x4;
typedef __attribute__((ext_vector_type(8))) __bf16 bf16x8;

__device__ __forceinline__ unsigned short f2bf_bits(float f) {
  union { float f; unsigned int u; } v; v.f = f;
  unsigned int u = v.u;
  unsigned int lsb = (u >> 16) & 1u;
  u += 0x7fffu + lsb;                 // round-to-nearest-even
  return (unsigned short)(u >> 16);
}

// ---- merged: convert x, convert W, degree histogram (block-range split) ----
__global__ void k_prep(const float* __restrict__ x, unsigned short* __restrict__ xb, int nx4,
                       const float* __restrict__ W, unsigned short* __restrict__ Wb, int nw4,
                       const int* __restrict__ dst, int* __restrict__ cnt, int E,
                       int bx, int bw) {
  const int b = blockIdx.x;
  if (b < bx) {
    int i = b * 256 + threadIdx.x;
    if (i < nx4) {
      float4 v = reinterpret_cast<const float4*>(x)[i];
      ushort4 o;
      o.x = f2bf_bits(v.x); o.y = f2bf_bits(v.y);
      o.z = f2bf_bits(v.z); o.w = f2bf_bits(v.w);
      reinterpret_cast<ushort4*>(xb)[i] = o;
    }
  } else if (b < bx + bw) {
    int i = (b - bx) * 256 + threadIdx.x;
    if (i < nw4) {
      float4 v = reinterpret_cast<const float4*>(W)[i];
      ushort4 o;
      o.x = f2bf_bits(v.x); o.y = f2bf_bits(v.y);
      o.z = f2bf_bits(v.z); o.w = f2bf_bits(v.w);
      reinterpret_cast<ushort4*>(Wb)[i] = o;
    }
  } else {
    int e = (b - bx - bw) * 256 + threadIdx.x;
    if (e < E) atomicAdd(&cnt[dst[e] * CPAD], 1);
  }
}

// ---- per-256-node block sums of (padded) degree counters ----
__global__ void k_bsum(const int* __restrict__ cnt, int* __restrict__ bsum, int n) {
  int t = threadIdx.x;
  int i = blockIdx.x * 256 + t;
  int v = (i < n) ? cnt[(size_t)i * CPAD] : 0;
  #pragma unroll
  for (int off = 32; off; off >>= 1) v += __shfl_down(v, off, 64);
  __shared__ int ws[4];
  if ((t & 63) == 0) ws[t >> 6] = v;
  __syncthreads();
  if (t == 0) bsum[blockIdx.x] = ws[0] + ws[1] + ws[2] + ws[3];
}

// ---- merged scan: each block redundantly scans bsum (nb<=256), then
//      block-local scan of padded cnt -> rowptr (exclusive, rowptr[0]=0) ----
__global__ void k_scanf(const int* __restrict__ cnt, const int* __restrict__ bsum,
                        int* __restrict__ rowptr, int n, int nb) {
  int t = threadIdx.x, lane = t & 63, w = t >> 6;
  __shared__ int ws1[4], ws2[4], sboff;

  // phase 1: exclusive prefix of bsum at index blockIdx.x (redundant per block)
  int v0 = (t < nb) ? bsum[t] : 0;
  int s0 = v0;
  #pragma unroll
  for (int off = 1; off < 64; off <<= 1) {
    int u = __shfl_up(s0, off, 64);
    if (lane >= off) s0 += u;
  }
  if (lane == 63) ws1[w] = s0;
  __syncthreads();
  if (t == blockIdx.x) {
    int add0 = 0;
    for (int j = 0; j < w; ++j) add0 += ws1[j];
    sboff = s0 + add0 - v0;            // exclusive offset for this block
  }
  __syncthreads();

  // phase 2: scan this block's 256 counters
  int i = blockIdx.x * 256 + t;
  int v = (i < n) ? cnt[(size_t)i * CPAD] : 0;
  int s = v;
  #pragma unroll
  for (int off = 1; off < 64; off <<= 1) {
    int u = __shfl_up(s, off, 64);
    if (lane >= off) s += u;
  }
  if (lane == 63) ws2[w] = s;
  __syncthreads();
  int add = sboff;
  for (int j = 0; j < w; ++j) add += ws2[j];
  if (i < n) rowptr[i + 1] = s + add;
  if (i == 0) rowptr[0] = 0;
}

// ---- counting-sort fill of CSR neighbor lists (padded cursors) ----
__global__ void k_fill(const int* __restrict__ src, const int* __restrict__ dst,
                       const int* __restrict__ rowptr, int* __restrict__ cursor,
                       int* __restrict__ csr, int E) {
  int e = blockIdx.x * 256 + threadIdx.x;
  if (e < E) {
    int d = dst[e];
    int pos = atomicAdd(&cursor[(size_t)d * CPAD], 1);
    csr[rowptr[d] + pos] = src[e];
  }
}

// ---- per-node neighbor mean: ONE WAVE per node, 16B/lane gathers ----
__device__ __forceinline__ void acc8(float* s, uint4 r) {
  const unsigned int u[4] = {r.x, r.y, r.z, r.w};
  #pragma unroll
  for (int k = 0; k < 4; ++k) {
    union { unsigned int u; float f; } lo, hi;
    lo.u = u[k] << 16;
    hi.u = u[k] & 0xffff0000u;
    s[2 * k]     += lo.f;
    s[2 * k + 1] += hi.f;
  }
}

__global__ __launch_bounds__(256) void k_aggregate(
    const unsigned short* __restrict__ xb,
    const int* __restrict__ rowptr,
    const int* __restrict__ csr,
    unsigned short* __restrict__ meanb, int Nn) {
  const int wid = blockIdx.x * 4 + (threadIdx.x >> 6);   // node id
  const int lane = threadIdx.x & 63;
  if (wid >= Nn) return;
  const int beg = rowptr[wid];
  const int deg = rowptr[wid + 1] - beg;
  float s[8] = {};
  const size_t laneoff = (size_t)lane * 8;

  for (int base = 0; base < deg; base += 64) {
    const int rem = deg - base;
    const int cnt = rem < 64 ? rem : 64;
    int nidx = 0;
    if (lane < cnt) nidx = csr[beg + base + lane];   // 64 indices per load
    int j = 0;
    for (; j + 4 <= cnt; j += 4) {                   // 4 gathers in flight
      int u0 = __shfl(nidx, j, 64);
      int u1 = __shfl(nidx, j + 1, 64);
      int u2 = __shfl(nidx, j + 2, 64);
      int u3 = __shfl(nidx, j + 3, 64);
      uint4 r0 = *reinterpret_cast<const uint4*>(xb + (size_t)u0 * CI + laneoff);
      uint4 r1 = *reinterpret_cast<const uint4*>(xb + (size_t)u1 * CI + laneoff);
      uint4 r2 = *reinterpret_cast<const uint4*>(xb + (size_t)u2 * CI + laneoff);
      uint4 r3 = *reinterpret_cast<const uint4*>(xb + (size_t)u3 * CI + laneoff);
      acc8(s, r0); acc8(s, r1); acc8(s, r2); acc8(s, r3);
    }
    for (; j < cnt; ++j) {
      int u = __shfl(nidx, j, 64);
      uint4 r = *reinterpret_cast<const uint4*>(xb + (size_t)u * CI + laneoff);
      acc8(s, r);
    }
  }

  const float inv = 1.f / fmaxf((float)deg, 1.f);
  unsigned short ob[8];
  #pragma unroll
  for (int k = 0; k < 8; ++k) ob[k] = f2bf_bits(s[k] * inv);
  uint4 w;
  w.x = (unsigned int)ob[0] | ((unsigned int)ob[1] << 16);
  w.y = (unsigned int)ob[2] | ((unsigned int)ob[3] << 16);
  w.z = (unsigned int)ob[4] | ((unsigned int)ob[5] << 16);
  w.w = (unsigned int)ob[6] | ((unsigned int)ob[7] << 16);
  *reinterpret_cast<uint4*>(meanb + (size_t)wid * CI + laneoff) = w;
}

// ---- bf16 MFMA GEMM: out[M][512] = [xb|meanb][M][1024] . Wb[512][1024]^T + b ----
// BK=64, T2 chunk-swizzle staging, LDS-staged epilogue with linear float4 stores.
#define BM 128
#define BN 128
#define BK 64
#define EPAD 132   // f32 row pitch for epilogue LDS tile (16B-aligned, bank-safe)

__global__ __launch_bounds__(256) void k_gemm(
    const unsigned short* __restrict__ xb,
    const unsigned short* __restrict__ meanb,
    const unsigned short* __restrict__ Wb,
    const float* __restrict__ bias,
    float* __restrict__ out, int M) {
  __shared__ unsigned short lds_a[BM * BK];   // 16 KB
  __shared__ unsigned short lds_b[BN * BK];   // 16 KB
  const int tid = threadIdx.x;
  const int ntn = CO / BN;                       // 4

  // Bijective XCD-aware swizzle (m204 formula; nwg=1564 is NOT %8==0).
  const int nwg = gridDim.x;
  const int NX = 8;
  const int q = nwg / NX, r = nwg % NX;
  const int xcd = blockIdx.x % NX, lid = blockIdx.x / NX;
  const int wg = (xcd < r ? xcd * (q + 1) : r * (q + 1) + (xcd - r) * q) + lid;

  const int tm = wg / ntn, tn = wg % ntn;
  const int m0 = tm * BM, n0 = tn * BN;
  const int lane = tid & 63, w = tid >> 6;
  const int wm = w >> 1, wn = w & 1;
  const int lrow = lane & 15;

  // Staging geometry: 4 x (256 threads x 16B) = 128 rows x 64 cols (bf16).
  int arow[4], gra[4], acol8[4];               // hoisted out of K-loop
  #pragma unroll
  for (int i = 0; i < 4; ++i) {
    int idx = i * 256 + tid;
    arow[i] = idx >> 3;
    int sc = idx & 7;
    acol8[i] = (sc ^ (arow[i] & 7)) * 8;       // element offset within row
    int g = m0 + arow[i];
    gra[i] = g < M ? g : M - 1;
  }

  f32x4 acc[4][4] = {};

  #pragma unroll
  for (int half = 0; half < 2; ++half) {
    const unsigned short* __restrict__ A = half ? meanb : xb;
    const int koff = half * CI;
    for (int k0 = 0; k0 < CI; k0 += BK) {
      __syncthreads();
      #pragma unroll
      for (int i = 0; i < 4; ++i) {
        __builtin_amdgcn_global_load_lds(
          (const __attribute__((address_space(1))) unsigned int*)(uintptr_t)(A + (size_t)gra[i] * CI + k0 + acol8[i]),
          (__attribute__((address_space(3))) unsigned int*)(uintptr_t)(&lds_a[(size_t)(i * 256 + tid) * 8]), 16, 0, 0);
        __builtin_amdgcn_global_load_lds(
          (const __attribute__((address_space(1))) unsigned int*)(uintptr_t)(Wb + (size_t)(n0 + arow[i]) * (2 * CI) + koff + k0 + acol8[i]),
          (__attribute__((address_space(3))) unsigned int*)(uintptr_t)(&lds_b[(size_t)(i * 256 + tid) * 8]), 16, 0, 0);
      }
      __syncthreads();
      #pragma unroll
      for (int kk = 0; kk < 2; ++kk) {
        const int crd = (lane >> 4) + 4 * kk;  // which 8-elem chunk of the row
        bf16x8 af[4], bfr[4];
        #pragma unroll
        for (int mi = 0; mi < 4; ++mi) {
          const int rr = wm * 64 + mi * 16 + lrow;
          af[mi] = *reinterpret_cast<const bf16x8*>(&lds_a[rr * BK + ((crd ^ (rr & 7)) * 8)]);
        }
        #pragma unroll
        for (int ni = 0; ni < 4; ++ni) {
          const int rr = wn * 64 + ni * 16 + lrow;
          bfr[ni] = *reinterpret_cast<const bf16x8*>(&lds_b[rr * BK + ((crd ^ (rr & 7)) * 8)]);
        }
        #pragma unroll
        for (int mi = 0; mi < 4; ++mi)
          #pragma unroll
          for (int ni = 0; ni < 4; ++ni)
            acc[mi][ni] = __builtin_amdgcn_mfma_f32_16x16x32_bf16(af[mi], bfr[ni], acc[mi][ni], 0, 0, 0);
      }
    }
  }

  // ---- LDS-staged epilogue: 8 chunks of 16 rows x 128 cols, linear f32x4 stores ----
  float* lds_c = reinterpret_cast<float*>(lds_a);   // 16*EPAD*4 = 8448B <= 16KB
  const int lj = lane >> 4;
  float bv[4];
  #pragma unroll
  for (int ni = 0; ni < 4; ++ni) bv[ni] = bias[n0 + wn * 64 + ni * 16 + lrow];

  __syncthreads();   // all LDS reads of the K-loop complete before overlay
  #pragma unroll
  for (int cw = 0; cw < 2; ++cw) {
    #pragma unroll
    for (int mi = 0; mi < 4; ++mi) {
      if (wm == cw) {
        #pragma unroll
        for (int ni = 0; ni < 4; ++ni)
          #pragma unroll
          for (int j = 0; j < 4; ++j)
            lds_c[(lj * 4 + j) * EPAD + wn * 64 + ni * 16 + lrow] = acc[mi][ni][j] + bv[ni];
      }
      __syncthreads();
      #pragma unroll
      for (int p = 0; p < 2; ++p) {
        int linear = p * 256 + tid;          // 0..511
        int rl = linear >> 5;                // 0..15
        int c4 = (linear & 31) << 2;         // 0..124
        int row = m0 + cw * 64 + mi * 16 + rl;
        if (row < M) {
          float4 v = *reinterpret_cast<const float4*>(&lds_c[rl * EPAD + c4]);
          *reinterpret_cast<float4*>(&out[(size_t)row * CO + n0 + c4]) = v;
        }
      }
      __syncthreads();
    }
  }
}

extern "C" void kernel_launch(void* const* d_in, const int* in_sizes, int n_in,
                              void* d_out, int out_size, void* d_ws, size_t ws_size,
                              hipStream_t stream) {
  (void)n_in; (void)out_size; (void)ws_size;
  const float* x    = (const float*)d_in[0];
  const int*   ei   = (const int*)d_in[1];
  const float* W    = (const float*)d_in[2];
  const float* bias = (const float*)d_in[3];
  float* out = (float*)d_out;

  const int Nn = in_sizes[0] / CI;     // 50000
  const int E  = in_sizes[1] / 2;      // 800000
  const int* src = ei;
  const int* dst = ei + E;

  const int nblk = (Nn + 255) / 256;   // 196 scan blocks

  // workspace layout (~113 MB):
  int* cnt    = (int*)d_ws;                      // [Nn*CPAD]
  int* cursor = cnt + (size_t)Nn * CPAD;         // [Nn*CPAD]
  int* rowptr = cursor + (size_t)Nn * CPAD;      // [Nn+1]
  int* bsum   = rowptr + (Nn + 1);               // [nblk]
  int* csr    = bsum + nblk;                     // [E]
  uintptr_t p = (uintptr_t)(csr + E);
  p = (p + 255) & ~(uintptr_t)255;
  unsigned short* xb    = (unsigned short*)p;           // [Nn*CI] bf16
  unsigned short* meanb = xb + (size_t)Nn * CI;         // [Nn*CI] bf16
  unsigned short* Wb    = meanb + (size_t)Nn * CI;      // [CO*2CI] bf16

  hipMemsetAsync(cnt, 0, (size_t)2 * Nn * CPAD * sizeof(int), stream);  // cnt + cursor

  const int nx4 = (Nn * CI) / 4;          // 6,400,000
  const int nw4 = (CO * 2 * CI) / 4;      // 131,072
  const int bx = (nx4 + 255) / 256;       // 25000
  const int bw = (nw4 + 255) / 256;       // 512
  const int be = (E + 255) / 256;         // 3125
  k_prep<<<bx + bw + be, 256, 0, stream>>>(x, xb, nx4, W, Wb, nw4, dst, cnt, E, bx, bw);
  k_bsum<<<nblk, 256, 0, stream>>>(cnt, bsum, Nn);
  k_scanf<<<nblk, 256, 0, stream>>>(cnt, bsum, rowptr, Nn, nblk);
  k_fill<<<(E + 255) / 256, 256, 0, stream>>>(src, dst, rowptr, cursor, csr, E);
  k_aggregate<<<(Nn + 3) / 4, 256, 0, stream>>>(xb, rowptr, csr, meanb, Nn);

  const int mtiles = (Nn + BM - 1) / BM;  // 391
  k_gemm<<<mtiles * (CO / BN), 256, 0, stream>>>(xb, meanb, Wb, bias, out, Nn);
}

// Round 5
// 313.830 us; speedup vs baseline: 1.1557x; 1.0027x over previous
//
#include <hip/hip_runtime.h>
#include <stdint.h>

// Problem constants (PureSAGEConv): N=50000, C_in=512, C_out=512, E=800000
#define CI 512
#define CO 512
#define CPAD 8   // counter padding stride (ints): 4 counters per 128B line

typedef __attribute__((ext_vector_type(4))) float f32x4;
typedef __attribute__((ext_vector_type(8))) __bf16 bf16x8;

__device__ __forceinline__ unsigned short f2bf_bits(float f) {
  union { float f; unsigned int u; } v; v.f = f;
  unsigned int u = v.u;
  unsigned int lsb = (u >> 16) & 1u;
  u += 0x7fffu + lsb;                 // round-to-nearest-even
  return (unsigned short)(u >> 16);
}

// ---- merged: convert x, convert W, degree histogram (block-range split) ----
__global__ void k_prep(const float* __restrict__ x, unsigned short* __restrict__ xb, int nx4,
                       const float* __restrict__ W, unsigned short* __restrict__ Wb, int nw4,
                       const int* __restrict__ dst, int* __restrict__ cnt, int E,
                       int bx, int bw) {
  const int b = blockIdx.x;
  if (b < bx) {
    int i = b * 256 + threadIdx.x;
    if (i < nx4) {
      float4 v = reinterpret_cast<const float4*>(x)[i];
      ushort4 o;
      o.x = f2bf_bits(v.x); o.y = f2bf_bits(v.y);
      o.z = f2bf_bits(v.z); o.w = f2bf_bits(v.w);
      reinterpret_cast<ushort4*>(xb)[i] = o;
    }
  } else if (b < bx + bw) {
    int i = (b - bx) * 256 + threadIdx.x;
    if (i < nw4) {
      float4 v = reinterpret_cast<const float4*>(W)[i];
      ushort4 o;
      o.x = f2bf_bits(v.x); o.y = f2bf_bits(v.y);
      o.z = f2bf_bits(v.z); o.w = f2bf_bits(v.w);
      reinterpret_cast<ushort4*>(Wb)[i] = o;
    }
  } else {
    int e = (b - bx - bw) * 256 + threadIdx.x;
    if (e < E) atomicAdd(&cnt[dst[e] * CPAD], 1);
  }
}

// ---- per-256-node block sums of (padded) degree counters ----
__global__ void k_bsum(const int* __restrict__ cnt, int* __restrict__ bsum, int n) {
  int t = threadIdx.x;
  int i = blockIdx.x * 256 + t;
  int v = (i < n) ? cnt[(size_t)i * CPAD] : 0;
  #pragma unroll
  for (int off = 32; off; off >>= 1) v += __shfl_down(v, off, 64);
  __shared__ int ws[4];
  if ((t & 63) == 0) ws[t >> 6] = v;
  __syncthreads();
  if (t == 0) bsum[blockIdx.x] = ws[0] + ws[1] + ws[2] + ws[3];
}

// ---- merged scan: each block redundantly scans bsum (nb<=256), then
//      block-local scan of padded cnt -> rowptr (exclusive, rowptr[0]=0) ----
__global__ void k_scanf(const int* __restrict__ cnt, const int* __restrict__ bsum,
                        int* __restrict__ rowptr, int n, int nb) {
  int t = threadIdx.x, lane = t & 63, w = t >> 6;
  __shared__ int ws1[4], ws2[4], sboff;

  // phase 1: exclusive prefix of bsum at index blockIdx.x (redundant per block)
  int v0 = (t < nb) ? bsum[t] : 0;
  int s0 = v0;
  #pragma unroll
  for (int off = 1; off < 64; off <<= 1) {
    int u = __shfl_up(s0, off, 64);
    if (lane >= off) s0 += u;
  }
  if (lane == 63) ws1[w] = s0;
  __syncthreads();
  if (t == blockIdx.x) {
    int add0 = 0;
    for (int j = 0; j < w; ++j) add0 += ws1[j];
    sboff = s0 + add0 - v0;            // exclusive offset for this block
  }
  __syncthreads();

  // phase 2: scan this block's 256 counters
  int i = blockIdx.x * 256 + t;
  int v = (i < n) ? cnt[(size_t)i * CPAD] : 0;
  int s = v;
  #pragma unroll
  for (int off = 1; off < 64; off <<= 1) {
    int u = __shfl_up(s, off, 64);
    if (lane >= off) s += u;
  }
  if (lane == 63) ws2[w] = s;
  __syncthreads();
  int add = sboff;
  for (int j = 0; j < w; ++j) add += ws2[j];
  if (i < n) rowptr[i + 1] = s + add;
  if (i == 0) rowptr[0] = 0;
}

// ---- counting-sort fill of CSR neighbor lists (padded cursors) ----
__global__ void k_fill(const int* __restrict__ src, const int* __restrict__ dst,
                       const int* __restrict__ rowptr, int* __restrict__ cursor,
                       int* __restrict__ csr, int E) {
  int e = blockIdx.x * 256 + threadIdx.x;
  if (e < E) {
    int d = dst[e];
    int pos = atomicAdd(&cursor[(size_t)d * CPAD], 1);
    csr[rowptr[d] + pos] = src[e];
  }
}

// ---- per-node neighbor mean: ONE WAVE per node, 16B/lane gathers ----
__device__ __forceinline__ void acc8(float* s, uint4 r) {
  const unsigned int u[4] = {r.x, r.y, r.z, r.w};
  #pragma unroll
  for (int k = 0; k < 4; ++k) {
    union { unsigned int u; float f; } lo, hi;
    lo.u = u[k] << 16;
    hi.u = u[k] & 0xffff0000u;
    s[2 * k]     += lo.f;
    s[2 * k + 1] += hi.f;
  }
}

__global__ __launch_bounds__(256) void k_aggregate(
    const unsigned short* __restrict__ xb,
    const int* __restrict__ rowptr,
    const int* __restrict__ csr,
    unsigned short* __restrict__ meanb, int Nn) {
  const int wid = blockIdx.x * 4 + (threadIdx.x >> 6);   // node id
  const int lane = threadIdx.x & 63;
  if (wid >= Nn) return;
  const int beg = rowptr[wid];
  const int deg = rowptr[wid + 1] - beg;
  float s[8] = {};
  const size_t laneoff = (size_t)lane * 8;

  for (int base = 0; base < deg; base += 64) {
    const int rem = deg - base;
    const int cnt = rem < 64 ? rem : 64;
    int nidx = 0;
    if (lane < cnt) nidx = csr[beg + base + lane];   // 64 indices per load
    int j = 0;
    for (; j + 4 <= cnt; j += 4) {                   // 4 gathers in flight
      int u0 = __shfl(nidx, j, 64);
      int u1 = __shfl(nidx, j + 1, 64);
      int u2 = __shfl(nidx, j + 2, 64);
      int u3 = __shfl(nidx, j + 3, 64);
      uint4 r0 = *reinterpret_cast<const uint4*>(xb + (size_t)u0 * CI + laneoff);
      uint4 r1 = *reinterpret_cast<const uint4*>(xb + (size_t)u1 * CI + laneoff);
      uint4 r2 = *reinterpret_cast<const uint4*>(xb + (size_t)u2 * CI + laneoff);
      uint4 r3 = *reinterpret_cast<const uint4*>(xb + (size_t)u3 * CI + laneoff);
      acc8(s, r0); acc8(s, r1); acc8(s, r2); acc8(s, r3);
    }
    for (; j < cnt; ++j) {
      int u = __shfl(nidx, j, 64);
      uint4 r = *reinterpret_cast<const uint4*>(xb + (size_t)u * CI + laneoff);
      acc8(s, r);
    }
  }

  const float inv = 1.f / fmaxf((float)deg, 1.f);
  unsigned short ob[8];
  #pragma unroll
  for (int k = 0; k < 8; ++k) ob[k] = f2bf_bits(s[k] * inv);
  uint4 w;
  w.x = (unsigned int)ob[0] | ((unsigned int)ob[1] << 16);
  w.y = (unsigned int)ob[2] | ((unsigned int)ob[3] << 16);
  w.z = (unsigned int)ob[4] | ((unsigned int)ob[5] << 16);
  w.w = (unsigned int)ob[6] | ((unsigned int)ob[7] << 16);
  *reinterpret_cast<uint4*>(meanb + (size_t)wid * CI + laneoff) = w;
}

// ---- bf16 MFMA GEMM, pipelined: out[M][512] = [xb|meanb][M][1024].Wb^T + b ----
// BM=256 BN=128 BK=64, 8 waves (512 thr), 3-slot LDS ring (144 KB),
// counted vmcnt(12): 2 K-tiles of loads stay in flight across barriers.
#define BM 256
#define BN 128
#define BK 64
#define SLOT_SH 24576     // shorts per slot: A 16384 (32KB) + B 8192 (16KB)
#define BOFF 16384        // B base within slot (shorts)
#define EPAD 132          // f32 row pitch for epilogue LDS tile

#define WAITV(N) asm volatile("s_waitcnt vmcnt(" #N ")" ::: "memory")

__global__ __launch_bounds__(512) void k_gemm(
    const unsigned short* __restrict__ xb,
    const unsigned short* __restrict__ meanb,
    const unsigned short* __restrict__ Wb,
    const float* __restrict__ bias,
    float* __restrict__ out, int M) {
  __shared__ unsigned short lds[3 * SLOT_SH];   // 144 KB
  const int tid = threadIdx.x;

  // grid = 196 m-tiles x 4 n-tiles = 784 = 8*98: chunked XCD swizzle
  const int wg = (blockIdx.x & 7) * 98 + (blockIdx.x >> 3);
  const int tm = wg >> 2, tn = wg & 3;
  const int m0 = tm * BM, n0 = tn * BN;
  const int lane = tid & 63, wvid = tid >> 6;
  const int wm = wvid >> 2, wn = wvid & 3;      // 2M x 4N waves
  const int lrow = lane & 15;

  // staging geometry (T2 chunk swizzle: src chunk = stored-chunk ^ (row&7))
  int gra[4], asrc8[4];
  #pragma unroll
  for (int i = 0; i < 4; ++i) {
    int idx = i * 512 + tid;
    int r = idx >> 3;
    asrc8[i] = ((idx & 7) ^ (r & 7)) * 8;
    int g = m0 + r;
    gra[i] = g < M ? g : M - 1;
  }
  int brow[2], bsrc8[2];
  #pragma unroll
  for (int i = 0; i < 2; ++i) {
    int idx = i * 512 + tid;
    int r = idx >> 3;
    brow[i] = r;
    bsrc8[i] = ((idx & 7) ^ (r & 7)) * 8;
  }

  f32x4 acc[8][2] = {};

  // stage K-tile kt into slot s: 4 A-rounds + 2 B-rounds of global_load_lds
  auto stage = [&](int kt, int s) {
    const unsigned short* __restrict__ A = (kt < 8) ? xb : meanb;
    const int ka = (kt & 7) * 64;
    const int kw = kt * 64;
    unsigned short* sa = &lds[s * SLOT_SH];
    unsigned short* sb = sa + BOFF;
    #pragma unroll
    for (int i = 0; i < 4; ++i)
      __builtin_amdgcn_global_load_lds(
        (const __attribute__((address_space(1))) unsigned int*)(uintptr_t)(A + (size_t)gra[i] * CI + ka + asrc8[i]),
        (__attribute__((address_space(3))) unsigned int*)(uintptr_t)(&sa[(size_t)(i * 512 + tid) * 8]), 16, 0, 0);
    #pragma unroll
    for (int i = 0; i < 2; ++i)
      __builtin_amdgcn_global_load_lds(
        (const __attribute__((address_space(1))) unsigned int*)(uintptr_t)(Wb + (size_t)(n0 + brow[i]) * (2 * CI) + kw + bsrc8[i]),
        (__attribute__((address_space(3))) unsigned int*)(uintptr_t)(&sb[(size_t)(i * 512 + tid) * 8]), 16, 0, 0);
  };

  auto compute = [&](int s) {
    const unsigned short* __restrict__ La = &lds[s * SLOT_SH];
    const unsigned short* __restrict__ Lb = La + BOFF;
    #pragma unroll
    for (int kk = 0; kk < 2; ++kk) {
      const int crd = kk * 4 + (lane >> 4);
      bf16x8 af[8], bf[2];
      #pragma unroll
      for (int mi = 0; mi < 8; ++mi) {
        const int rr = wm * 128 + mi * 16 + lrow;
        af[mi] = *reinterpret_cast<const bf16x8*>(&La[rr * BK + ((crd ^ (rr & 7)) * 8)]);
      }
      #pragma unroll
      for (int ni = 0; ni < 2; ++ni) {
        const int rb = wn * 32 + ni * 16 + lrow;
        bf[ni] = *reinterpret_cast<const bf16x8*>(&Lb[rb * BK + ((crd ^ (rb & 7)) * 8)]);
      }
      __builtin_amdgcn_s_setprio(1);
      #pragma unroll
      for (int mi = 0; mi < 8; ++mi)
        #pragma unroll
        for (int ni = 0; ni < 2; ++ni)
          acc[mi][ni] = __builtin_amdgcn_mfma_f32_16x16x32_bf16(af[mi], bf[ni], acc[mi][ni], 0, 0, 0);
      __builtin_amdgcn_s_setprio(0);
    }
  };

  // prologue: 2 tiles in flight
  stage(0, 0);
  stage(1, 1);

  #pragma unroll
  for (int t = 0; t < 16; ++t) {
    if (t < 14) {
      stage(t + 2, (t + 2) % 3);   // ring slot (t+2)%3 == (t-1)%3: freed by t-1's end barrier
      WAITV(12);                    // oldest (tile t's 6 loads per thread) complete; 12 stay in flight
    } else if (t == 14) {
      WAITV(6);
    } else {
      WAITV(0);
    }
    __builtin_amdgcn_s_barrier();           // slot t ready for ALL waves
    __builtin_amdgcn_sched_barrier(0);
    compute(t % 3);
    __builtin_amdgcn_sched_barrier(0);
    __builtin_amdgcn_s_barrier();           // all waves done reading slot t%3
  }

  // ---- LDS-staged epilogue: 8 chunks of 32 rows x 128 cols, linear f32x4 stores ----
  __syncthreads();
  float* ldsf = reinterpret_cast<float*>(&lds[0]);   // 32*EPAD*4 = 16.9 KB
  const int lj = lane >> 4;
  float bv[2];
  #pragma unroll
  for (int ni = 0; ni < 2; ++ni) bv[ni] = bias[n0 + wn * 32 + ni * 16 + lrow];

  #pragma unroll
  for (int c = 0; c < 8; ++c) {
    if (wm == (c >> 2)) {
      #pragma unroll
      for (int mi2 = 0; mi2 < 2; ++mi2) {
        const int mi = (c & 3) * 2 + mi2;
        #pragma unroll
        for (int ni = 0; ni < 2; ++ni)
          #pragma unroll
          for (int j = 0; j < 4; ++j)
            ldsf[(mi2 * 16 + lj * 4 + j) * EPAD + wn * 32 + ni * 16 + lrow] = acc[mi][ni][j] + bv[ni];
      }
    }
    __syncthreads();
    #pragma unroll
    for (int p = 0; p < 2; ++p) {
      int linear = p * 512 + tid;           // 0..1023
      int rl = linear >> 5;                 // 0..31
      int c4 = (linear & 31) << 2;          // 0..124
      int row = m0 + c * 32 + rl;
      if (row < M) {
        float4 v = *reinterpret_cast<const float4*>(&ldsf[rl * EPAD + c4]);
        *reinterpret_cast<float4*>(&out[(size_t)row * CO + n0 + c4]) = v;
      }
    }
    __syncthreads();
  }
}

extern "C" void kernel_launch(void* const* d_in, const int* in_sizes, int n_in,
                              void* d_out, int out_size, void* d_ws, size_t ws_size,
                              hipStream_t stream) {
  (void)n_in; (void)out_size; (void)ws_size;
  const float* x    = (const float*)d_in[0];
  const int*   ei   = (const int*)d_in[1];
  const float* W    = (const float*)d_in[2];
  const float* bias = (const float*)d_in[3];
  float* out = (float*)d_out;

  const int Nn = in_sizes[0] / CI;     // 50000
  const int E  = in_sizes[1] / 2;      // 800000
  const int* src = ei;
  const int* dst = ei + E;

  const int nblk = (Nn + 255) / 256;   // 196 scan blocks

  // workspace layout (~113 MB):
  int* cnt    = (int*)d_ws;                      // [Nn*CPAD]
  int* cursor = cnt + (size_t)Nn * CPAD;         // [Nn*CPAD]
  int* rowptr = cursor + (size_t)Nn * CPAD;      // [Nn+1]
  int* bsum   = rowptr + (Nn + 1);               // [nblk]
  int* csr    = bsum + nblk;                     // [E]
  uintptr_t p = (uintptr_t)(csr + E);
  p = (p + 255) & ~(uintptr_t)255;
  unsigned short* xb    = (unsigned short*)p;           // [Nn*CI] bf16
  unsigned short* meanb = xb + (size_t)Nn * CI;         // [Nn*CI] bf16
  unsigned short* Wb    = meanb + (size_t)Nn * CI;      // [CO*2CI] bf16

  hipMemsetAsync(cnt, 0, (size_t)2 * Nn * CPAD * sizeof(int), stream);  // cnt + cursor

  const int nx4 = (Nn * CI) / 4;          // 6,400,000
  const int nw4 = (CO * 2 * CI) / 4;      // 131,072
  const int bx = (nx4 + 255) / 256;       // 25000
  const int bw = (nw4 + 255) / 256;       // 512
  const int be = (E + 255) / 256;         // 3125
  k_prep<<<bx + bw + be, 256, 0, stream>>>(x, xb, nx4, W, Wb, nw4, dst, cnt, E, bx, bw);
  k_bsum<<<nblk, 256, 0, stream>>>(cnt, bsum, Nn);
  k_scanf<<<nblk, 256, 0, stream>>>(cnt, bsum, rowptr, Nn, nblk);
  k_fill<<<(E + 255) / 256, 256, 0, stream>>>(src, dst, rowptr, cursor, csr, E);
  k_aggregate<<<(Nn + 3) / 4, 256, 0, stream>>>(xb, rowptr, csr, meanb, Nn);

  const int mtiles = (Nn + BM - 1) / BM;  // 196
  k_gemm<<<mtiles * (CO / BN), 512, 0, stream>>>(xb, meanb, Wb, bias, out, Nn);
}